// Round 3
// baseline (2169.099 us; speedup 1.0000x reference)
//
#include <hip/hip_runtime.h>
#include <hip/hip_cooperative_groups.h>
#include <math.h>

namespace cg = cooperative_groups;

#define FILTERS 8
#define NB 32
#define NT 16
#define NH 64
#define NW 64
#define NC 3
#define GATES 32   // 4*FILTERS

__device__ __forceinline__ float hard_sigmoid(float v) {
    return fminf(fmaxf(fmaf(0.2f, v, 0.5f), 0.0f), 1.0f);
}

// tanh(x) = 1 - 2/(exp(2x)+1); exp(2x) = 2^(x * 2*log2(e)). Saturates correctly.
__device__ __forceinline__ float fast_tanh(float v) {
    float e = __builtin_amdgcn_exp2f(v * 2.8853900817779268f);
    return 1.0f - 2.0f * __builtin_amdgcn_rcpf(e + 1.0f);
}

// ---------------- fused cooperative kernel: all 16 steps + head ----------------
__global__ __launch_bounds__(256, 2) void convlstm_fused(
    const float* __restrict__ x,     // (B,T,H,W,C)
    const float* __restrict__ Wx,    // (3,3,3,32)
    const float* __restrict__ Wh,    // (3,3,8,32)
    const float* __restrict__ bias,  // (32,)
    const float* __restrict__ Wout,  // (32768, 4)
    const float* __restrict__ bout,  // (4,)
    float* __restrict__ h0,          // (B,H,W,8) ping
    float* __restrict__ h1,          // (B,H,W,8) pong
    float* __restrict__ partial,     // (512, 4)
    float* __restrict__ out)         // (B, 4)
{
    cg::grid_group grid = cg::this_grid();

    const int tid = blockIdx.x * 256 + threadIdx.x;   // 0 .. B*H*W-1
    const int xc = tid & (NW - 1);
    const int yc = (tid >> 6) & (NH - 1);
    const int bi = tid >> 12;
    const size_t pix = (size_t)tid * FILTERS;         // (B,H,W,F) flat

    float c[FILTERS];
    #pragma unroll
    for (int i = 0; i < FILTERS; ++i) c[i] = 0.0f;

    const float* xb = x + (size_t)bi * NT * NH * NW * NC;

    #pragma unroll 1   // keep the step body rolled: I$-resident across 16 iters
    for (int t = 0; t < NT; ++t) {
        const float* hin  = (t & 1) ? h0 : h1;
        float*       hout = (t & 1) ? h1 : h0;

        float z[GATES];
        #pragma unroll
        for (int i = 0; i < GATES; ++i) z[i] = bias[i];

        const float* xt = xb + (size_t)t * NH * NW * NC;

        #pragma unroll
        for (int ky = 0; ky < 3; ++ky) {
            int yy = yc + ky - 1;
            if ((unsigned)yy >= NH) continue;      // wave-uniform skip
            #pragma unroll
            for (int kx = 0; kx < 3; ++kx) {
                int xx = xc + kx - 1;
                if ((unsigned)xx >= NW) continue;  // lane-masked

                const float* xp = xt + (yy * NW + xx) * NC;
                float x0 = xp[0], x1 = xp[1], x2 = xp[2];
                const float* wxp = Wx + ((ky * 3 + kx) * NC) * GATES;
                #pragma unroll
                for (int co = 0; co < GATES; ++co) {
                    float acc = z[co];
                    acc = fmaf(x0, wxp[co], acc);
                    acc = fmaf(x1, wxp[GATES + co], acc);
                    acc = fmaf(x2, wxp[2 * GATES + co], acc);
                    z[co] = acc;
                }

                if (t > 0) {
                    const float* hp = hin + (((size_t)bi * NH + yy) * NW + xx) * FILTERS;
                    float4 hv0 = *(const float4*)hp;
                    float4 hv1 = *(const float4*)(hp + 4);
                    float hv[8] = {hv0.x, hv0.y, hv0.z, hv0.w,
                                   hv1.x, hv1.y, hv1.z, hv1.w};
                    const float* whp = Wh + ((ky * 3 + kx) * FILTERS) * GATES;
                    #pragma unroll
                    for (int ci = 0; ci < FILTERS; ++ci)
                        #pragma unroll
                        for (int co = 0; co < GATES; ++co)
                            z[co] = fmaf(hv[ci], whp[ci * GATES + co], z[co]);
                }
            }
        }

        float hn[FILTERS];
        #pragma unroll
        for (int f = 0; f < FILTERS; ++f) {
            float ig = hard_sigmoid(z[f]);
            float fg = hard_sigmoid(z[8 + f]);
            float gg = fast_tanh(z[16 + f]);
            float og = hard_sigmoid(z[24 + f]);
            float cc = fmaf(fg, c[f], ig * gg);
            c[f] = cc;
            hn[f] = og * fast_tanh(cc);
        }

        *(float4*)(hout + pix)     = make_float4(hn[0], hn[1], hn[2], hn[3]);
        *(float4*)(hout + pix + 4) = make_float4(hn[4], hn[5], hn[6], hn[7]);

        __threadfence();
        grid.sync();
    }

    // ---- head stage 1: block = (batch, chunk); h_final is h1 (t=15 wrote h1)
    {
        const int b = blockIdx.x >> 4;
        const int chunk = blockIdx.x & 15;
        const float* hb = h1 + (size_t)b * 32768 + chunk * 2048;
        const float* wb = Wout + (size_t)(chunk * 2048) * 4;

        float acc[4] = {0.f, 0.f, 0.f, 0.f};
        #pragma unroll
        for (int it = 0; it < 8; ++it) {
            int i = it * 256 + threadIdx.x;
            float hv = hb[i];
            float4 w = *(const float4*)(wb + (size_t)i * 4);
            acc[0] = fmaf(hv, w.x, acc[0]);
            acc[1] = fmaf(hv, w.y, acc[1]);
            acc[2] = fmaf(hv, w.z, acc[2]);
            acc[3] = fmaf(hv, w.w, acc[3]);
        }
        #pragma unroll
        for (int j = 0; j < 4; ++j)
            #pragma unroll
            for (int off = 32; off >= 1; off >>= 1)
                acc[j] += __shfl_down(acc[j], off, 64);

        __shared__ float red[4][4];
        int lane = threadIdx.x & 63, wv = threadIdx.x >> 6;
        if (lane == 0) {
            #pragma unroll
            for (int j = 0; j < 4; ++j) red[wv][j] = acc[j];
        }
        __syncthreads();
        if (threadIdx.x == 0) {
            #pragma unroll
            for (int j = 0; j < 4; ++j)
                partial[(size_t)blockIdx.x * 4 + j] =
                    red[0][j] + red[1][j] + red[2][j] + red[3][j];
        }
    }

    __threadfence();
    grid.sync();

    // ---- head stage 2: block 0, thread b < 32
    if (blockIdx.x == 0 && threadIdx.x < NB) {
        int b = threadIdx.x;
        float logit[4] = {bout[0], bout[1], bout[2], bout[3]};
        #pragma unroll
        for (int k = 0; k < 16; ++k) {
            const float* p = partial + (size_t)(b * 16 + k) * 4;
            logit[0] += p[0]; logit[1] += p[1]; logit[2] += p[2]; logit[3] += p[3];
        }
        float m = fmaxf(fmaxf(logit[0], logit[1]), fmaxf(logit[2], logit[3]));
        float e[4], s = 0.f;
        #pragma unroll
        for (int j = 0; j < 4; ++j) { e[j] = expf(logit[j] - m); s += e[j]; }
        float inv = 1.0f / s;
        #pragma unroll
        for (int j = 0; j < 4; ++j) out[b * 4 + j] = e[j] * inv;
    }
}

// ---------------- fallback (non-cooperative) path ----------------
__global__ __launch_bounds__(256) void convlstm_step(
    const float* __restrict__ x, const float* __restrict__ Wx,
    const float* __restrict__ Wh, const float* __restrict__ bias,
    const float* __restrict__ h_in, float* __restrict__ h_out,
    float* __restrict__ c_buf, int t, int first)
{
    int tid = blockIdx.x * blockDim.x + threadIdx.x;
    int xc = tid & (NW - 1);
    int yc = (tid >> 6) & (NH - 1);
    int bi = tid >> 12;

    float z[GATES];
    #pragma unroll
    for (int i = 0; i < GATES; ++i) z[i] = bias[i];

    const float* xt = x + (((size_t)bi * NT + t) * NH * NW) * NC;

    #pragma unroll
    for (int ky = 0; ky < 3; ++ky) {
        int yy = yc + ky - 1;
        if ((unsigned)yy >= NH) continue;
        #pragma unroll
        for (int kx = 0; kx < 3; ++kx) {
            int xx = xc + kx - 1;
            if ((unsigned)xx >= NW) continue;
            const float* xp = xt + (yy * NW + xx) * NC;
            float x0 = xp[0], x1 = xp[1], x2 = xp[2];
            const float* wxp = Wx + ((ky * 3 + kx) * NC) * GATES;
            #pragma unroll
            for (int co = 0; co < GATES; ++co) {
                float acc = z[co];
                acc = fmaf(x0, wxp[co], acc);
                acc = fmaf(x1, wxp[GATES + co], acc);
                acc = fmaf(x2, wxp[2 * GATES + co], acc);
                z[co] = acc;
            }
            if (!first) {
                const float* hp = h_in + (((size_t)bi * NH + yy) * NW + xx) * FILTERS;
                float4 hv0 = *(const float4*)hp;
                float4 hv1 = *(const float4*)(hp + 4);
                float hv[8] = {hv0.x, hv0.y, hv0.z, hv0.w,
                               hv1.x, hv1.y, hv1.z, hv1.w};
                const float* whp = Wh + ((ky * 3 + kx) * FILTERS) * GATES;
                #pragma unroll
                for (int ci = 0; ci < FILTERS; ++ci)
                    #pragma unroll
                    for (int co = 0; co < GATES; ++co)
                        z[co] = fmaf(hv[ci], whp[ci * GATES + co], z[co]);
            }
        }
    }

    size_t pix = (size_t)tid * FILTERS;
    float c_old[8];
    if (first) {
        #pragma unroll
        for (int i = 0; i < 8; ++i) c_old[i] = 0.0f;
    } else {
        float4 ca = *(const float4*)(c_buf + pix);
        float4 cb = *(const float4*)(c_buf + pix + 4);
        c_old[0]=ca.x; c_old[1]=ca.y; c_old[2]=ca.z; c_old[3]=ca.w;
        c_old[4]=cb.x; c_old[5]=cb.y; c_old[6]=cb.z; c_old[7]=cb.w;
    }
    float hn[8], cn[8];
    #pragma unroll
    for (int f = 0; f < 8; ++f) {
        float ig = hard_sigmoid(z[f]);
        float fg = hard_sigmoid(z[8 + f]);
        float gg = fast_tanh(z[16 + f]);
        float og = hard_sigmoid(z[24 + f]);
        float cc = fmaf(fg, c_old[f], ig * gg);
        cn[f] = cc;
        hn[f] = og * fast_tanh(cc);
    }
    *(float4*)(c_buf + pix)     = make_float4(cn[0], cn[1], cn[2], cn[3]);
    *(float4*)(c_buf + pix + 4) = make_float4(cn[4], cn[5], cn[6], cn[7]);
    *(float4*)(h_out + pix)     = make_float4(hn[0], hn[1], hn[2], hn[3]);
    *(float4*)(h_out + pix + 4) = make_float4(hn[4], hn[5], hn[6], hn[7]);
}

__global__ __launch_bounds__(256) void head_partial(
    const float* __restrict__ h, const float* __restrict__ Wout,
    float* __restrict__ partial)
{
    const int b = blockIdx.x >> 4;
    const int chunk = blockIdx.x & 15;
    const int tid = threadIdx.x;
    const float* hb = h + (size_t)b * 32768 + chunk * 2048;
    const float* wb = Wout + (size_t)(chunk * 2048) * 4;
    float acc[4] = {0.f, 0.f, 0.f, 0.f};
    #pragma unroll
    for (int it = 0; it < 8; ++it) {
        int i = it * 256 + tid;
        float hv = hb[i];
        float4 w = *(const float4*)(wb + (size_t)i * 4);
        acc[0]=fmaf(hv,w.x,acc[0]); acc[1]=fmaf(hv,w.y,acc[1]);
        acc[2]=fmaf(hv,w.z,acc[2]); acc[3]=fmaf(hv,w.w,acc[3]);
    }
    #pragma unroll
    for (int j = 0; j < 4; ++j)
        #pragma unroll
        for (int off = 32; off >= 1; off >>= 1)
            acc[j] += __shfl_down(acc[j], off, 64);
    __shared__ float red[4][4];
    int lane = tid & 63, wv = tid >> 6;
    if (lane == 0)
        #pragma unroll
        for (int j = 0; j < 4; ++j) red[wv][j] = acc[j];
    __syncthreads();
    if (tid == 0)
        #pragma unroll
        for (int j = 0; j < 4; ++j)
            partial[(size_t)blockIdx.x * 4 + j] =
                red[0][j] + red[1][j] + red[2][j] + red[3][j];
}

__global__ __launch_bounds__(64) void head_finish(
    const float* __restrict__ partial, const float* __restrict__ bout,
    float* __restrict__ out)
{
    int b = threadIdx.x;
    if (b >= NB) return;
    float logit[4] = {bout[0], bout[1], bout[2], bout[3]};
    #pragma unroll
    for (int k = 0; k < 16; ++k) {
        const float* p = partial + (size_t)(b * 16 + k) * 4;
        logit[0]+=p[0]; logit[1]+=p[1]; logit[2]+=p[2]; logit[3]+=p[3];
    }
    float m = fmaxf(fmaxf(logit[0], logit[1]), fmaxf(logit[2], logit[3]));
    float e[4], s = 0.f;
    #pragma unroll
    for (int j = 0; j < 4; ++j) { e[j] = expf(logit[j] - m); s += e[j]; }
    float inv = 1.0f / s;
    #pragma unroll
    for (int j = 0; j < 4; ++j) out[b * 4 + j] = e[j] * inv;
}

extern "C" void kernel_launch(void* const* d_in, const int* in_sizes, int n_in,
                              void* d_out, int out_size, void* d_ws, size_t ws_size,
                              hipStream_t stream) {
    const float* x    = (const float*)d_in[0];
    const float* Wx   = (const float*)d_in[1];
    const float* Wh   = (const float*)d_in[2];
    const float* b    = (const float*)d_in[3];
    const float* Wout = (const float*)d_in[4];
    const float* bout = (const float*)d_in[5];
    float* out = (float*)d_out;

    const size_t state_elems = (size_t)NB * NH * NW * FILTERS;  // 1,048,576
    float* h0 = (float*)d_ws;
    float* h1 = h0 + state_elems;
    float* partial = h1 + state_elems;          // 512*4
    float* cb = partial + 512 * 4;              // fallback c buffer

    void* args[] = {(void*)&x, (void*)&Wx, (void*)&Wh, (void*)&b,
                    (void*)&Wout, (void*)&bout,
                    (void*)&h0, (void*)&h1, (void*)&partial, (void*)&out};

    hipError_t err = hipLaunchCooperativeKernel(convlstm_fused,
                                                dim3(512), dim3(256),
                                                args, 0, stream);
    if (err != hipSuccess) {
        // fallback: classic multi-kernel path
        dim3 block(256);
        dim3 grid((NB * NH * NW) / 256);
        for (int t = 0; t < NT; ++t) {
            const float* hin = (t & 1) ? h0 : h1;
            float* hout      = (t & 1) ? h1 : h0;
            convlstm_step<<<grid, block, 0, stream>>>(x, Wx, Wh, b, hin, hout,
                                                      cb, t, (t == 0) ? 1 : 0);
        }
        head_partial<<<512, 256, 0, stream>>>(h1, Wout, partial);
        head_finish<<<1, 64, 0, stream>>>(partial, bout, out);
    }
}

// Round 4
// 765.896 us; speedup vs baseline: 2.8321x; 2.8321x over previous
//
#include <hip/hip_runtime.h>
#include <math.h>

#define FILTERS 8
#define NB 32
#define NT 16
#define NH 64
#define NW 64
#define NC 3
#define GATES 32   // 4*FILTERS

// LDS tile: 11 planes (0-2: x channels, 3-10: h filters), 6 rows, 66 cols
// (zero-padded halo). Planar layout -> all conv reads are consecutive-lane
// ds_read_b32 (conflict-free).
#define TROWS 6
#define TCOLS 66
#define LIDX(p, r, c) (((p) * TROWS + (r)) * TCOLS + (c))

__device__ __forceinline__ float hard_sigmoid(float v) {
    return fminf(fmaxf(fmaf(0.2f, v, 0.5f), 0.0f), 1.0f);
}

// tanh(x) = 1 - 2/(exp(2x)+1). Validated absmax 0.0 in round 2/3.
__device__ __forceinline__ float fast_tanh(float v) {
    float e = __builtin_amdgcn_exp2f(v * 2.8853900817779268f);
    return 1.0f - 2.0f * __builtin_amdgcn_rcpf(e + 1.0f);
}

// Block = 512 threads: {filter-half (2)} x {4 rows} x {64 cols} of one batch.
// Grid = 32 batches x 16 row-groups = 512 blocks -> 2 blocks/CU, 4 waves/SIMD.
__global__ __launch_bounds__(512, 4) void convlstm_step(
    const float* __restrict__ x,     // (B,T,H,W,C)
    const float* __restrict__ Wx,    // (3,3,3,32)
    const float* __restrict__ Wh,    // (3,3,8,32)
    const float* __restrict__ bias,  // (32,)
    const float* __restrict__ h_in,  // (B,H,W,8)
    float* __restrict__ h_out,       // (B,H,W,8)
    float* __restrict__ c_buf,       // (B,H,W,8)
    int t, int first)
{
    __shared__ float lds[11 * TROWS * TCOLS];

    const int bi  = blockIdx.x >> 4;
    const int r0  = (blockIdx.x & 15) << 2;   // first output row of this block
    const int tid = threadIdx.x;
    const int half = tid >> 8;                // 0: filters 0-3, 1: filters 4-7
    const int idx  = tid & 255;
    const int yloc = idx >> 6;                // 0..3
    const int xloc = idx & 63;

    const float* xt = x + (((size_t)bi * NT + t) * NH * NW) * NC;

    // ---- cooperative staging: x tile (3 planes) + h tile (8 planes) ----
    for (int i = tid; i < TROWS * TCOLS; i += 512) {
        int row_l = i / TCOLS;
        int col_l = i - row_l * TCOLS;
        int yg = r0 - 1 + row_l;
        int xg = col_l - 1;
        float xv0 = 0.f, xv1 = 0.f, xv2 = 0.f;
        float hv0 = 0.f, hv1 = 0.f, hv2 = 0.f, hv3 = 0.f;
        float hv4 = 0.f, hv5 = 0.f, hv6 = 0.f, hv7 = 0.f;
        if ((unsigned)yg < NH && (unsigned)xg < NW) {
            const float* xp = xt + (yg * NW + xg) * NC;
            xv0 = xp[0]; xv1 = xp[1]; xv2 = xp[2];
            if (!first) {
                const float* hp = h_in + (((size_t)bi * NH + yg) * NW + xg) * FILTERS;
                float4 a = *(const float4*)hp;
                float4 b4 = *(const float4*)(hp + 4);
                hv0 = a.x; hv1 = a.y; hv2 = a.z; hv3 = a.w;
                hv4 = b4.x; hv5 = b4.y; hv6 = b4.z; hv7 = b4.w;
            }
        }
        lds[LIDX(0, row_l, col_l)]  = xv0;
        lds[LIDX(1, row_l, col_l)]  = xv1;
        lds[LIDX(2, row_l, col_l)]  = xv2;
        lds[LIDX(3, row_l, col_l)]  = hv0;
        lds[LIDX(4, row_l, col_l)]  = hv1;
        lds[LIDX(5, row_l, col_l)]  = hv2;
        lds[LIDX(6, row_l, col_l)]  = hv3;
        lds[LIDX(7, row_l, col_l)]  = hv4;
        lds[LIDX(8, row_l, col_l)]  = hv5;
        lds[LIDX(9, row_l, col_l)]  = hv6;
        lds[LIDX(10, row_l, col_l)] = hv7;
    }
    __syncthreads();

    // ---- conv: 16 gate channels (4 filters x 4 gates) for this half ----
    // z[g*4+fi] = gate g of filter (half*4+fi)
    float z[16];
    #pragma unroll
    for (int g = 0; g < 4; ++g)
        #pragma unroll
        for (int fi = 0; fi < 4; ++fi)
            z[g * 4 + fi] = bias[g * 8 + half * 4 + fi];

    #pragma unroll
    for (int ky = 0; ky < 3; ++ky) {
        #pragma unroll
        for (int kx = 0; kx < 3; ++kx) {
            const int rr = yloc + ky;   // 0..5
            const int cc = xloc + kx;   // 0..65

            float xa = lds[LIDX(0, rr, cc)];
            float xb = lds[LIDX(1, rr, cc)];
            float xc2 = lds[LIDX(2, rr, cc)];
            const float* wxp = Wx + ((ky * 3 + kx) * NC) * GATES + half * 4;
            #pragma unroll
            for (int g = 0; g < 4; ++g)
                #pragma unroll
                for (int fi = 0; fi < 4; ++fi) {
                    int co = g * 8 + fi;
                    float acc = z[g * 4 + fi];
                    acc = fmaf(xa,  wxp[co], acc);
                    acc = fmaf(xb,  wxp[GATES + co], acc);
                    acc = fmaf(xc2, wxp[2 * GATES + co], acc);
                    z[g * 4 + fi] = acc;
                }

            if (!first) {
                float hv[FILTERS];
                #pragma unroll
                for (int ci = 0; ci < FILTERS; ++ci)
                    hv[ci] = lds[LIDX(3 + ci, rr, cc)];
                const float* whp = Wh + ((ky * 3 + kx) * FILTERS) * GATES + half * 4;
                #pragma unroll
                for (int ci = 0; ci < FILTERS; ++ci)
                    #pragma unroll
                    for (int g = 0; g < 4; ++g)
                        #pragma unroll
                        for (int fi = 0; fi < 4; ++fi)
                            z[g * 4 + fi] = fmaf(hv[ci], whp[ci * GATES + g * 8 + fi],
                                                 z[g * 4 + fi]);
            }
        }
    }

    // ---- gates + state update (4 filters of this half) ----
    const int gpix = (bi << 12) | ((r0 + yloc) << 6) | xloc;
    const size_t off = (size_t)gpix * FILTERS + half * 4;

    float c_old[4] = {0.f, 0.f, 0.f, 0.f};
    if (!first) {
        float4 cv = *(const float4*)(c_buf + off);
        c_old[0] = cv.x; c_old[1] = cv.y; c_old[2] = cv.z; c_old[3] = cv.w;
    }

    float hn[4], cn[4];
    #pragma unroll
    for (int fi = 0; fi < 4; ++fi) {
        float ig = hard_sigmoid(z[0 * 4 + fi]);
        float fg = hard_sigmoid(z[1 * 4 + fi]);
        float gg = fast_tanh(z[2 * 4 + fi]);
        float og = hard_sigmoid(z[3 * 4 + fi]);
        float cc = fmaf(fg, c_old[fi], ig * gg);
        cn[fi] = cc;
        hn[fi] = og * fast_tanh(cc);
    }

    *(float4*)(c_buf + off) = make_float4(cn[0], cn[1], cn[2], cn[3]);
    *(float4*)(h_out + off) = make_float4(hn[0], hn[1], hn[2], hn[3]);
}

// Stage 1: 512 blocks (32 batches x 16 chunks); each reduces 2048 elements.
__global__ __launch_bounds__(256) void head_partial(
    const float* __restrict__ h,     // (B, 32768)
    const float* __restrict__ Wout,  // (32768, 4)
    float* __restrict__ partial)     // (B*16, 4)
{
    const int b = blockIdx.x >> 4;
    const int chunk = blockIdx.x & 15;
    const int tid = threadIdx.x;
    const float* hb = h + (size_t)b * 32768 + chunk * 2048;
    const float* wb = Wout + (size_t)(chunk * 2048) * 4;

    float acc[4] = {0.f, 0.f, 0.f, 0.f};
    #pragma unroll
    for (int it = 0; it < 8; ++it) {
        int i = it * 256 + tid;
        float hv = hb[i];
        float4 w = *(const float4*)(wb + (size_t)i * 4);
        acc[0] = fmaf(hv, w.x, acc[0]);
        acc[1] = fmaf(hv, w.y, acc[1]);
        acc[2] = fmaf(hv, w.z, acc[2]);
        acc[3] = fmaf(hv, w.w, acc[3]);
    }

    #pragma unroll
    for (int j = 0; j < 4; ++j)
        #pragma unroll
        for (int off = 32; off >= 1; off >>= 1)
            acc[j] += __shfl_down(acc[j], off, 64);

    __shared__ float red[4][4];
    int lane = tid & 63, wv = tid >> 6;
    if (lane == 0) {
        #pragma unroll
        for (int j = 0; j < 4; ++j) red[wv][j] = acc[j];
    }
    __syncthreads();
    if (tid == 0) {
        #pragma unroll
        for (int j = 0; j < 4; ++j)
            partial[(size_t)blockIdx.x * 4 + j] =
                red[0][j] + red[1][j] + red[2][j] + red[3][j];
    }
}

__global__ __launch_bounds__(64) void head_finish(
    const float* __restrict__ partial,  // (B*16, 4)
    const float* __restrict__ bout,     // (4,)
    float* __restrict__ out)            // (B, 4)
{
    int b = threadIdx.x;
    if (b >= NB) return;
    float logit[4] = {bout[0], bout[1], bout[2], bout[3]};
    #pragma unroll
    for (int k = 0; k < 16; ++k) {
        const float* p = partial + (size_t)(b * 16 + k) * 4;
        logit[0] += p[0]; logit[1] += p[1]; logit[2] += p[2]; logit[3] += p[3];
    }
    float m = fmaxf(fmaxf(logit[0], logit[1]), fmaxf(logit[2], logit[3]));
    float e[4], s = 0.f;
    #pragma unroll
    for (int j = 0; j < 4; ++j) { e[j] = expf(logit[j] - m); s += e[j]; }
    float inv = 1.0f / s;
    #pragma unroll
    for (int j = 0; j < 4; ++j) out[b * 4 + j] = e[j] * inv;
}

extern "C" void kernel_launch(void* const* d_in, const int* in_sizes, int n_in,
                              void* d_out, int out_size, void* d_ws, size_t ws_size,
                              hipStream_t stream) {
    const float* x    = (const float*)d_in[0];
    const float* Wx   = (const float*)d_in[1];
    const float* Wh   = (const float*)d_in[2];
    const float* b    = (const float*)d_in[3];
    const float* Wout = (const float*)d_in[4];
    const float* bout = (const float*)d_in[5];
    float* out = (float*)d_out;

    const size_t state_elems = (size_t)NB * NH * NW * FILTERS;  // 1,048,576
    float* h0 = (float*)d_ws;
    float* h1 = h0 + state_elems;
    float* cb = h1 + state_elems;
    float* partial = cb + state_elems;   // 512*4 floats

    dim3 block(512);
    dim3 grid(NB * 16);   // 512 blocks: (batch, row-group)

    for (int t = 0; t < NT; ++t) {
        const float* hin = (t & 1) ? h0 : h1;   // t=0 ignores hin (first=1)
        float* hout      = (t & 1) ? h1 : h0;
        convlstm_step<<<grid, block, 0, stream>>>(x, Wx, Wh, b, hin, hout, cb,
                                                  t, (t == 0) ? 1 : 0);
    }
    // t = 15 wrote h1
    head_partial<<<512, 256, 0, stream>>>(h1, Wout, partial);
    head_finish<<<1, 64, 0, stream>>>(partial, bout, out);
}

// Round 5
// 205.974 us; speedup vs baseline: 10.5309x; 3.7184x over previous
//
#include <hip/hip_runtime.h>
#include <math.h>

#define FILTERS 8
#define NB 32
#define NT 16
#define NH 64
#define NW 64
#define NC 3
#define GATES 32   // 4*FILTERS

// LDS tile: 11 planes (0-2: x channels, 3-10: h filters), 6 rows, 66 cols
// (zero-padded halo). Planar layout -> all conv reads are consecutive-lane
// ds_read_b32 (conflict-free).
#define TROWS 6
#define TCOLS 66
#define LIDX(p, r, c) (((p) * TROWS + (r)) * TCOLS + (c))

__device__ __forceinline__ float hard_sigmoid(float v) {
    return fminf(fmaxf(fmaf(0.2f, v, 0.5f), 0.0f), 1.0f);
}

// tanh(x) = 1 - 2/(exp(2x)+1). Validated absmax 0.0 in rounds 2-4.
__device__ __forceinline__ float fast_tanh(float v) {
    float e = __builtin_amdgcn_exp2f(v * 2.8853900817779268f);
    return 1.0f - 2.0f * __builtin_amdgcn_rcpf(e + 1.0f);
}

// Block = 512 threads: {filter-half (2)} x {4 rows} x {64 cols} of one batch.
// Grid = 32 batches x 16 row-groups = 512 blocks -> 2 blocks/CU, 4 waves/SIMD.
__global__ __launch_bounds__(512, 4) void convlstm_step(
    const float* __restrict__ x,     // (B,T,H,W,C)
    const float* __restrict__ Wx,    // (3,3,3,32)
    const float* __restrict__ Wh,    // (3,3,8,32)
    const float* __restrict__ bias,  // (32,)
    const float* __restrict__ h_in,  // (B,H,W,8)
    float* __restrict__ h_out,       // (B,H,W,8)
    float* __restrict__ c_buf,       // (B,H,W,8)
    int t, int first)
{
    __shared__ float lds[11 * TROWS * TCOLS];

    const int bi  = blockIdx.x >> 4;
    const int r0  = (blockIdx.x & 15) << 2;   // first output row of this block
    const int tid = threadIdx.x;
    // Wave-uniform (waves = 64 consecutive tids; 256-boundary is wave-aligned).
    // readfirstlane pins it to an SGPR so ALL weight addresses stay scalar ->
    // batched s_load instead of 1584 per-lane global_load_dword (round-4 bug).
    const int half = __builtin_amdgcn_readfirstlane(tid >> 8);
    const int idx  = tid & 255;
    const int yloc = idx >> 6;                // 0..3
    const int xloc = idx & 63;

    const float* xt = x + (((size_t)bi * NT + t) * NH * NW) * NC;

    // ---- cooperative staging: x tile (3 planes) + h tile (8 planes) ----
    for (int i = tid; i < TROWS * TCOLS; i += 512) {
        int row_l = i / TCOLS;
        int col_l = i - row_l * TCOLS;
        int yg = r0 - 1 + row_l;
        int xg = col_l - 1;
        float xv0 = 0.f, xv1 = 0.f, xv2 = 0.f;
        float hv0 = 0.f, hv1 = 0.f, hv2 = 0.f, hv3 = 0.f;
        float hv4 = 0.f, hv5 = 0.f, hv6 = 0.f, hv7 = 0.f;
        if ((unsigned)yg < NH && (unsigned)xg < NW) {
            const float* xp = xt + (yg * NW + xg) * NC;
            xv0 = xp[0]; xv1 = xp[1]; xv2 = xp[2];
            if (!first) {
                const float* hp = h_in + (((size_t)bi * NH + yg) * NW + xg) * FILTERS;
                float4 a = *(const float4*)hp;
                float4 b4 = *(const float4*)(hp + 4);
                hv0 = a.x; hv1 = a.y; hv2 = a.z; hv3 = a.w;
                hv4 = b4.x; hv5 = b4.y; hv6 = b4.z; hv7 = b4.w;
            }
        }
        lds[LIDX(0, row_l, col_l)]  = xv0;
        lds[LIDX(1, row_l, col_l)]  = xv1;
        lds[LIDX(2, row_l, col_l)]  = xv2;
        lds[LIDX(3, row_l, col_l)]  = hv0;
        lds[LIDX(4, row_l, col_l)]  = hv1;
        lds[LIDX(5, row_l, col_l)]  = hv2;
        lds[LIDX(6, row_l, col_l)]  = hv3;
        lds[LIDX(7, row_l, col_l)]  = hv4;
        lds[LIDX(8, row_l, col_l)]  = hv5;
        lds[LIDX(9, row_l, col_l)]  = hv6;
        lds[LIDX(10, row_l, col_l)] = hv7;
    }
    __syncthreads();

    // ---- conv: 16 gate channels (4 filters x 4 gates) for this half ----
    // z[g*4+fi] = gate g of filter (half*4+fi)
    float z[16];
    #pragma unroll
    for (int g = 0; g < 4; ++g)
        #pragma unroll
        for (int fi = 0; fi < 4; ++fi)
            z[g * 4 + fi] = bias[g * 8 + half * 4 + fi];

    #pragma unroll
    for (int ky = 0; ky < 3; ++ky) {
        #pragma unroll
        for (int kx = 0; kx < 3; ++kx) {
            const int rr = yloc + ky;   // 0..5
            const int cc = xloc + kx;   // 0..65

            float xa  = lds[LIDX(0, rr, cc)];
            float xb  = lds[LIDX(1, rr, cc)];
            float xc2 = lds[LIDX(2, rr, cc)];
            const float* wxp = Wx + ((ky * 3 + kx) * NC) * GATES + half * 4;
            #pragma unroll
            for (int g = 0; g < 4; ++g)
                #pragma unroll
                for (int fi = 0; fi < 4; ++fi) {
                    int co = g * 8 + fi;
                    float acc = z[g * 4 + fi];
                    acc = fmaf(xa,  wxp[co], acc);
                    acc = fmaf(xb,  wxp[GATES + co], acc);
                    acc = fmaf(xc2, wxp[2 * GATES + co], acc);
                    z[g * 4 + fi] = acc;
                }

            if (!first) {
                float hv[FILTERS];
                #pragma unroll
                for (int ci = 0; ci < FILTERS; ++ci)
                    hv[ci] = lds[LIDX(3 + ci, rr, cc)];
                const float* whp = Wh + ((ky * 3 + kx) * FILTERS) * GATES + half * 4;
                #pragma unroll
                for (int ci = 0; ci < FILTERS; ++ci)
                    #pragma unroll
                    for (int g = 0; g < 4; ++g)
                        #pragma unroll
                        for (int fi = 0; fi < 4; ++fi)
                            z[g * 4 + fi] = fmaf(hv[ci], whp[ci * GATES + g * 8 + fi],
                                                 z[g * 4 + fi]);
            }
        }
    }

    // ---- gates + state update (4 filters of this half) ----
    const int gpix = (bi << 12) | ((r0 + yloc) << 6) | xloc;
    const size_t off = (size_t)gpix * FILTERS + half * 4;

    float c_old[4] = {0.f, 0.f, 0.f, 0.f};
    if (!first) {
        float4 cv = *(const float4*)(c_buf + off);
        c_old[0] = cv.x; c_old[1] = cv.y; c_old[2] = cv.z; c_old[3] = cv.w;
    }

    float hn[4], cn[4];
    #pragma unroll
    for (int fi = 0; fi < 4; ++fi) {
        float ig = hard_sigmoid(z[0 * 4 + fi]);
        float fg = hard_sigmoid(z[1 * 4 + fi]);
        float gg = fast_tanh(z[2 * 4 + fi]);
        float og = hard_sigmoid(z[3 * 4 + fi]);
        float cc = fmaf(fg, c_old[fi], ig * gg);
        cn[fi] = cc;
        hn[fi] = og * fast_tanh(cc);
    }

    *(float4*)(c_buf + off) = make_float4(cn[0], cn[1], cn[2], cn[3]);
    *(float4*)(h_out + off) = make_float4(hn[0], hn[1], hn[2], hn[3]);
}

// Stage 1: 512 blocks (32 batches x 16 chunks); each reduces 2048 elements.
__global__ __launch_bounds__(256) void head_partial(
    const float* __restrict__ h,     // (B, 32768)
    const float* __restrict__ Wout,  // (32768, 4)
    float* __restrict__ partial)     // (B*16, 4)
{
    const int b = blockIdx.x >> 4;
    const int chunk = blockIdx.x & 15;
    const int tid = threadIdx.x;
    const float* hb = h + (size_t)b * 32768 + chunk * 2048;
    const float* wb = Wout + (size_t)(chunk * 2048) * 4;

    float acc[4] = {0.f, 0.f, 0.f, 0.f};
    #pragma unroll
    for (int it = 0; it < 8; ++it) {
        int i = it * 256 + tid;
        float hv = hb[i];
        float4 w = *(const float4*)(wb + (size_t)i * 4);
        acc[0] = fmaf(hv, w.x, acc[0]);
        acc[1] = fmaf(hv, w.y, acc[1]);
        acc[2] = fmaf(hv, w.z, acc[2]);
        acc[3] = fmaf(hv, w.w, acc[3]);
    }

    #pragma unroll
    for (int j = 0; j < 4; ++j)
        #pragma unroll
        for (int off = 32; off >= 1; off >>= 1)
            acc[j] += __shfl_down(acc[j], off, 64);

    __shared__ float red[4][4];
    int lane = tid & 63, wv = tid >> 6;
    if (lane == 0) {
        #pragma unroll
        for (int j = 0; j < 4; ++j) red[wv][j] = acc[j];
    }
    __syncthreads();
    if (tid == 0) {
        #pragma unroll
        for (int j = 0; j < 4; ++j)
            partial[(size_t)blockIdx.x * 4 + j] =
                red[0][j] + red[1][j] + red[2][j] + red[3][j];
    }
}

__global__ __launch_bounds__(64) void head_finish(
    const float* __restrict__ partial,  // (B*16, 4)
    const float* __restrict__ bout,     // (4,)
    float* __restrict__ out)            // (B, 4)
{
    int b = threadIdx.x;
    if (b >= NB) return;
    float logit[4] = {bout[0], bout[1], bout[2], bout[3]};
    #pragma unroll
    for (int k = 0; k < 16; ++k) {
        const float* p = partial + (size_t)(b * 16 + k) * 4;
        logit[0] += p[0]; logit[1] += p[1]; logit[2] += p[2]; logit[3] += p[3];
    }
    float m = fmaxf(fmaxf(logit[0], logit[1]), fmaxf(logit[2], logit[3]));
    float e[4], s = 0.f;
    #pragma unroll
    for (int j = 0; j < 4; ++j) { e[j] = expf(logit[j] - m); s += e[j]; }
    float inv = 1.0f / s;
    #pragma unroll
    for (int j = 0; j < 4; ++j) out[b * 4 + j] = e[j] * inv;
}

extern "C" void kernel_launch(void* const* d_in, const int* in_sizes, int n_in,
                              void* d_out, int out_size, void* d_ws, size_t ws_size,
                              hipStream_t stream) {
    const float* x    = (const float*)d_in[0];
    const float* Wx   = (const float*)d_in[1];
    const float* Wh   = (const float*)d_in[2];
    const float* b    = (const float*)d_in[3];
    const float* Wout = (const float*)d_in[4];
    const float* bout = (const float*)d_in[5];
    float* out = (float*)d_out;

    const size_t state_elems = (size_t)NB * NH * NW * FILTERS;  // 1,048,576
    float* h0 = (float*)d_ws;
    float* h1 = h0 + state_elems;
    float* cb = h1 + state_elems;
    float* partial = cb + state_elems;   // 512*4 floats

    dim3 block(512);
    dim3 grid(NB * 16);   // 512 blocks: (batch, row-group)

    for (int t = 0; t < NT; ++t) {
        const float* hin = (t & 1) ? h0 : h1;   // t=0 ignores hin (first=1)
        float* hout      = (t & 1) ? h1 : h0;
        convlstm_step<<<grid, block, 0, stream>>>(x, Wx, Wh, b, hin, hout, cb,
                                                  t, (t == 0) ? 1 : 0);
    }
    // t = 15 wrote h1
    head_partial<<<512, 256, 0, stream>>>(h1, Wout, partial);
    head_finish<<<1, 64, 0, stream>>>(partial, bout, out);
}